// Round 7
// baseline (148.965 us; speedup 1.0000x reference)
//
#include <hip/hip_runtime.h>
#include <math.h>

// B=8, C=64, H=W=64, N=4096, N4=1024. bf16 MFMA, fp32 accumulate.
//
// ALGEBRAIC RESTRUCTURE (R2): no full-resolution projections.
//  Stage1: softmax(qp^T K(x)) == softmax((w_K^T qp)^T x); PV on raw x;
//          out1 = w_V (x a^T) + b_V applied at 1024 width in comb.
//  Stage2: Q(x)^T kp == x^T (w_Q^T kp) + gamma_m (per-key bias in flash2).
// R4: P kept in registers (cvt_pk_bf16 + permlane32/16 quad-transpose).
// R7 (= R5 + ONE isolated change, bisecting R6's NaN): K operand loaded
//     DIRECT from global into registers, single-buffered per iteration
//     (fragment layout == global layout, no swizzle; removes K DMA + half
//     the LDS reads). Loop/barrier structure, __expf softmax, NSPLIT=8
//     flash1 all IDENTICAL to R5 (last passing).
// Pipeline (4 kernels): prep, flash1 (split 8), comb1kv, flash2 (KS=2
// internal K-split, per-key bias, fused gamma+residual -> out).
// Flash: S^T/O^T form, 32 q/wave, V via async-DMA LDS (chunk-rot swizzle),
// UNSHIFTED softmax (p=e^s, scores O(8), safe in fp32).

typedef __bf16 bf16;
typedef __attribute__((ext_vector_type(4))) __bf16 bf16x4;
typedef __attribute__((ext_vector_type(8))) __bf16 bf16x8;
typedef __attribute__((ext_vector_type(4))) float f32x4;

__device__ __forceinline__ void gl_lds16(const bf16* g, bf16* l) {
    __builtin_amdgcn_global_load_lds(
        (const __attribute__((address_space(1))) unsigned int*)g,
        (__attribute__((address_space(3))) unsigned int*)l,
        16, 0, 0);
}

// pack 2 f32 -> 2 bf16 in one u32 (lo = a, hi = b)
__device__ __forceinline__ unsigned cvtpk(float a, float b) {
    unsigned r;
    asm("v_cvt_pk_bf16_f32 %0, %1, %2" : "=v"(r) : "v"(a), "v"(b));
    return r;
}
// swap lanes [32..63] of a with [0..31] of b
__device__ __forceinline__ void swap32(unsigned &a, unsigned &b) {
    asm("v_permlane32_swap_b32 %0, %1" : "+v"(a), "+v"(b));
}
// swap lanes [16..31],[48..63] of a with [0..15],[32..47] of b
__device__ __forceinline__ void swap16(unsigned &a, unsigned &b) {
    asm("v_permlane16_swap_b32 %0, %1" : "+v"(a), "+v"(b));
}

// ---------------------------------------------------------------------------
// Weight fragments for a 64x64 1x1-conv as MFMA A-operand.
// WT=0: rows of W (W[o][c]); WT=1: transposed (W^T)[o][c] = W[c][o].
// ---------------------------------------------------------------------------
struct WFrag { bf16x8 f[4][2]; };

template<int WT>
__device__ __forceinline__ WFrag load_wfrag(const float* __restrict__ W, int lane) {
    const int c16 = lane & 15, q4 = lane >> 4;
    WFrag wf;
    #pragma unroll
    for (int to = 0; to < 4; ++to)
        #pragma unroll
        for (int h = 0; h < 2; ++h) {
            bf16 tmp[8];
            if (WT == 0) {
                const float* wp = W + (16 * to + c16) * 64 + q4 * 8 + 32 * h;
                float4 f0 = *(const float4*)wp;
                float4 f1 = *(const float4*)(wp + 4);
                tmp[0] = (bf16)f0.x; tmp[1] = (bf16)f0.y;
                tmp[2] = (bf16)f0.z; tmp[3] = (bf16)f0.w;
                tmp[4] = (bf16)f1.x; tmp[5] = (bf16)f1.y;
                tmp[6] = (bf16)f1.z; tmp[7] = (bf16)f1.w;
            } else {
                #pragma unroll
                for (int j = 0; j < 8; ++j)
                    tmp[j] = (bf16)W[(q4 * 8 + 32 * h + j) * 64 + 16 * to + c16];
            }
            wf.f[to][h] = *(bf16x8*)tmp;
        }
    return wf;
}

// ---------------------------------------------------------------------------
// Per-wave projection of TN*16 rows x 64ch from LDS src (stride 72).
// OUT=0: global (B,N,64) row-major; OUT=1: global (B,64,N); OUT=2: LDS (72).
// ---------------------------------------------------------------------------
template<int OUT>
__device__ __forceinline__ void proj_run(
    const bf16* __restrict__ src, int TN, const WFrag& wf, const float* __restrict__ Bs,
    bf16* __restrict__ Y, int N, int b, int gn0, bf16* __restrict__ Yl, int lane)
{
    const int c16 = lane & 15, q4 = lane >> 4;
    for (int tn = 0; tn < TN; ++tn) {
        bf16x8 xb0 = *(const bf16x8*)&src[(16 * tn + c16) * 72 + q4 * 8];
        bf16x8 xb1 = *(const bf16x8*)&src[(16 * tn + c16) * 72 + q4 * 8 + 32];
        #pragma unroll
        for (int to = 0; to < 4; ++to) {
            f32x4 acc = (f32x4){0.f, 0.f, 0.f, 0.f};
            acc = __builtin_amdgcn_mfma_f32_16x16x32_bf16(wf.f[to][0], xb0, acc, 0, 0, 0);
            acc = __builtin_amdgcn_mfma_f32_16x16x32_bf16(wf.f[to][1], xb1, acc, 0, 0, 0);
            float bias[4] = {0.f, 0.f, 0.f, 0.f};
            if (Bs) {
                float4 b4 = *(const float4*)(Bs + 16 * to + q4 * 4);
                bias[0] = b4.x; bias[1] = b4.y; bias[2] = b4.z; bias[3] = b4.w;
            }
            if (OUT == 0) {
                bf16x4 yv;
                #pragma unroll
                for (int r = 0; r < 4; ++r) yv[r] = (bf16)(acc[r] + bias[r]);
                *(bf16x4*)(Y + ((size_t)b * N + gn0 + 16 * tn + c16) * 64 + 16 * to + 4 * q4) = yv;
            } else if (OUT == 1) {
                #pragma unroll
                for (int r = 0; r < 4; ++r)
                    Y[((size_t)b * 64 + 16 * to + 4 * q4 + r) * N + gn0 + 16 * tn + c16] =
                        (bf16)(acc[r] + bias[r]);
            } else {
                bf16x4 yv;
                #pragma unroll
                for (int r = 0; r < 4; ++r) yv[r] = (bf16)(acc[r] + bias[r]);
                *(bf16x4*)&Yl[(16 * tn + c16) * 72 + 16 * to + 4 * q4] = yv;
            }
        }
    }
}

// ---------------------------------------------------------------------------
// prep: x (B,64,4096) fp32 -> xt (B,4096,64) bf16 (transposed raw x),
// xn (B,64,4096) bf16 (cast raw x), qkt (B,1024,64) = w_K^T (w_q xp + b_q).
// ---------------------------------------------------------------------------
__global__ __launch_bounds__(256) void prep_kernel(
    const float* __restrict__ x,
    const float* __restrict__ w_q, const float* __restrict__ b_q,
    const float* __restrict__ w_K,
    bf16* __restrict__ xt, bf16* __restrict__ xn, bf16* __restrict__ qkt)
{
    __shared__ float tile[128 * 65];
    __shared__ __align__(16) bf16 xpb[32 * 72];
    __shared__ __align__(16) bf16 qtile[32 * 72];
    const int t  = threadIdx.x;
    const int h2 = blockIdx.x;
    const int b  = blockIdx.y;
    const int n0 = h2 * 128;

    #pragma unroll
    for (int i = 0; i < 32; ++i) {
        int lin = i * 256 + t;
        int n = lin & 127, c = lin >> 7;
        tile[n * 65 + c] = x[((size_t)b * 64 + c) * 4096 + n0 + n];
    }
    __syncthreads();
    {   // 2x2 avg pool of the 128-n tile -> 32 pooled rows
        int wp = t & 31, c0 = (t >> 5) * 8;
        bf16 tmp[8];
        #pragma unroll
        for (int j = 0; j < 8; ++j) {
            float a = tile[(2 * wp) * 65 + c0 + j] + tile[(2 * wp + 1) * 65 + c0 + j]
                    + tile[(64 + 2 * wp) * 65 + c0 + j] + tile[(64 + 2 * wp + 1) * 65 + c0 + j];
            tmp[j] = (bf16)(0.25f * a);
        }
        *(bf16x8*)&xpb[wp * 72 + c0] = *(bf16x8*)tmp;
    }
    __syncthreads();

    // xt: transposed bf16 cast (coalesced 16B stores)
    #pragma unroll
    for (int i = 0; i < 4; ++i) {
        int slot = i * 256 + t;
        int n = slot >> 3, c0 = (slot & 7) * 8;
        bf16 tmp[8];
        #pragma unroll
        for (int j = 0; j < 8; ++j) tmp[j] = (bf16)tile[n * 65 + c0 + j];
        *(bf16x8*)&xt[((size_t)b * 4096 + n0 + n) * 64 + c0] = *(bf16x8*)tmp;
    }
    // xn: straight bf16 cast (channel-major)
    #pragma unroll
    for (int i = 0; i < 4; ++i) {
        int slot = i * 256 + t;
        int c = slot >> 4, n8 = slot & 15;
        bf16 tmp[8];
        #pragma unroll
        for (int j = 0; j < 8; ++j) tmp[j] = (bf16)tile[(n8 * 8 + j) * 65 + c];
        *(bf16x8*)&xn[((size_t)b * 64 + c) * 4096 + n0 + n8 * 8] = *(bf16x8*)tmp;
    }
    // wave 3: qkt chain (qtile = w_q xp + b_q; qkt = w_K^T qtile)
    if ((t >> 6) == 3) {
        const int lane = t & 63;
        WFrag wfq  = load_wfrag<0>(w_q, lane);
        WFrag wfKT = load_wfrag<1>(w_K, lane);
        proj_run<2>(xpb, 2, wfq, b_q, nullptr, 0, 0, 0, qtile, lane);
        asm volatile("s_waitcnt lgkmcnt(0)" ::: "memory");
        proj_run<0>(qtile, 2, wfKT, nullptr, qkt, 1024, b, h2 * 32, nullptr, lane);
    }
}

// ---------------------------------------------------------------------------
// Flash, S^T/O^T, U*16 q/wave. KS=1: 4 waves. KS=2: 8 waves, two 4-wave
// groups each own half of L, unnormalized O,l combined via LDS (exact:
// softmax unshifted). K operand: direct global->register loads at iteration
// top (fragment layout == global layout). V: async-DMA LDS, double-buffered.
// P kept in registers (cvt_pk + permlane quad-transpose).
// BIAS: per-key fp32 additive score bias.
//   Qt: (B,NQ,64), Kt: (B,L,64), Vn: (B,64,L) bf16.
//   MODE=1: split partials, Opart (B,S,NQ,64) normalized bf16 + l.
//   MODE=2: final: out_f = gamma*O/l + resid (fp32, channel-major).
// ---------------------------------------------------------------------------
template<int NSPLIT, int MODE, int U, int KS, bool BIAS>
__global__ __launch_bounds__(256 * KS, KS == 1 ? 3 : 2) void flash_kernel(
    const bf16* __restrict__ Qt, const bf16* __restrict__ Kt,
    const bf16* __restrict__ Vn, int NQ, int L,
    bf16* __restrict__ Opart, float* __restrict__ Lbuf,
    float* __restrict__ out_f, const float* __restrict__ resid,
    const float* __restrict__ gamma_p, const float* __restrict__ Gb)
{
    const int tid  = threadIdx.x;
    const int lane = tid & 63;
    const int w    = tid >> 6;
    const int wl   = w & 3;          // wave-in-group
    const int g    = w >> 2;         // K-split group
    const int c16  = lane & 15;
    const int q4   = lane >> 4;
    const int b    = blockIdx.y;
    const int n0   = blockIdx.x * (64 * U) + wl * (16 * U);
    const int s    = (NSPLIT > 1) ? blockIdx.z : 0;
    const int SL   = L / (NSPLIT * KS);
    const int k0   = (s * KS + g) * SL;
    const int ntiles = SL / 64;

    // V double-buffer arena [KS][2][4096] bf16; KS=2 epilogue overlays
    // fp32 combine scratch (34.8KB) -> 36KB arena.
    constexpr int SMEM_B = (KS == 2) ? 36864 : 16384;
    __shared__ __align__(16) char smem[SMEM_B];
    bf16* Vsm = (bf16*)smem;

    const int rl8 = lane >> 3;               // 0..7
    const int cg  = ((lane & 7) - rl8) & 7;  // rotated source chunk (V DMA)

    const bf16* Kb = Kt + (size_t)b * L * 64;
    const bf16* Vb = Vn + (size_t)b * 64 * L;

    bf16x8 bq[U][2];
    #pragma unroll
    for (int u = 0; u < U; ++u) {
        const bf16* qrow = Qt + ((size_t)b * NQ + n0 + 16 * u + c16) * 64 + q4 * 8;
        bq[u][0] = *(const bf16x8*)(qrow);
        bq[u][1] = *(const bf16x8*)(qrow + 32);
    }

    f32x4 O[U][4];
    #pragma unroll
    for (int u = 0; u < U; ++u)
        #pragma unroll
        for (int gi = 0; gi < 4; ++gi) O[u][gi] = (f32x4){0.f, 0.f, 0.f, 0.f};
    float l_acc[U];
    #pragma unroll
    for (int u = 0; u < U; ++u) l_acc[u] = 0.f;

    // V prologue stage (tile 0)
    #pragma unroll
    for (int j = 0; j < 2; ++j) {
        const int row = 16 * wl + 8 * j + rl8;
        gl_lds16(Vb + (size_t)row * L + k0 + cg * 8,
                 &Vsm[(g * 2 + 0) * 4096 + (16 * wl + 8 * j) * 64]);
    }
    __syncthreads();

    for (int it = 0; it < ntiles; ++it) {
        const int buf = it & 1;
        if (it + 1 < ntiles) {
            const int kn = k0 + (it + 1) * 64;
            #pragma unroll
            for (int j = 0; j < 2; ++j) {
                const int row = 16 * wl + 8 * j + rl8;
                gl_lds16(Vb + (size_t)row * L + kn + cg * 8,
                         &Vsm[(g * 2 + (buf ^ 1)) * 4096 + (16 * wl + 8 * j) * 64]);
            }
        }

        // ---- K fragments: direct global loads (layout matches operand) ----
        bf16x8 kr[8];
        {
            const bf16* kbase = Kb + (size_t)(k0 + it * 64) * 64;
            #pragma unroll
            for (int t = 0; t < 4; ++t) {
                kr[2 * t]     = *(const bf16x8*)(kbase + (16 * t + c16) * 64 + q4 * 8);
                kr[2 * t + 1] = *(const bf16x8*)(kbase + (16 * t + c16) * 64 + 32 + q4 * 8);
            }
        }

        // ---- S^T, K-frags shared across query sets ----
        f32x4 sv[U][4];
        #pragma unroll
        for (int t = 0; t < 4; ++t) {
            #pragma unroll
            for (int u = 0; u < U; ++u) {
                f32x4 z = (f32x4){0.f, 0.f, 0.f, 0.f};
                z = __builtin_amdgcn_mfma_f32_16x16x32_bf16(kr[2 * t], bq[u][0], z, 0, 0, 0);
                sv[u][t] = __builtin_amdgcn_mfma_f32_16x16x32_bf16(kr[2 * t + 1], bq[u][1], z, 0, 0, 0);
            }
        }

        // ---- per-key bias (stage 2): key = k0+64it+16t+4q4+r ----
        float4 gb[4];
        if (BIAS) {
            #pragma unroll
            for (int t = 0; t < 4; ++t)
                gb[t] = *(const float4*)&Gb[(size_t)b * 1024 + k0 + it * 64 + 16 * t + 4 * q4];
        }

        // ---- unshifted softmax + in-register P quad-transpose ----
        bf16x8 pfs[U][2];
        #pragma unroll
        for (int u = 0; u < U; ++u) {
            #pragma unroll
            for (int t = 0; t < 4; ++t)
                #pragma unroll
                for (int r = 0; r < 4; ++r) {
                    float sval = sv[u][t][r];
                    if (BIAS) sval += ((const float*)&gb[t])[r];
                    float p = __expf(sval);
                    sv[u][t][r] = p;
                    l_acc[u] += p;
                }
            unsigned A0 = cvtpk(sv[u][0][0], sv[u][0][1]);
            unsigned A1 = cvtpk(sv[u][0][2], sv[u][0][3]);
            unsigned A2 = cvtpk(sv[u][2][0], sv[u][2][1]);
            unsigned A3 = cvtpk(sv[u][2][2], sv[u][2][3]);
            unsigned B0 = cvtpk(sv[u][1][0], sv[u][1][1]);
            unsigned B1 = cvtpk(sv[u][1][2], sv[u][1][3]);
            unsigned B2 = cvtpk(sv[u][3][0], sv[u][3][1]);
            unsigned B3 = cvtpk(sv[u][3][2], sv[u][3][3]);
            swap32(A0, B0); swap16(A0, B0);
            swap32(A1, B1); swap16(A1, B1);
            swap32(A2, B2); swap16(A2, B2);
            swap32(A3, B3); swap16(A3, B3);
            union { unsigned wd[4]; bf16x8 v; } p0, p1;
            p0.wd[0] = A0; p0.wd[1] = A1; p0.wd[2] = B0; p0.wd[3] = B1;
            p1.wd[0] = A2; p1.wd[1] = A3; p1.wd[2] = B2; p1.wd[3] = B3;
            pfs[u][0] = p0.v;
            pfs[u][1] = p1.v;
        }

        // ---- PV: V-frags from LDS (swizzled reads), shared across sets ----
        #pragma unroll
        for (int h = 0; h < 2; ++h) {
            #pragma unroll
            for (int gi = 0; gi < 4; ++gi) {
                bf16x8 av = *(const bf16x8*)&Vsm[(g * 2 + buf) * 4096 +
                                                 (16 * gi + c16) * 64 + ((4 * h + q4 + c16) & 7) * 8];
                #pragma unroll
                for (int u = 0; u < U; ++u)
                    O[u][gi] = __builtin_amdgcn_mfma_f32_16x16x32_bf16(av, pfs[u][h], O[u][gi], 0, 0, 0);
            }
        }
        __syncthreads();
    }

    // ---- reduce l across quads ----
    float l_tot[U];
    #pragma unroll
    for (int u = 0; u < U; ++u) {
        float l = l_acc[u];
        l += __shfl_xor(l, 16);
        l += __shfl_xor(l, 32);
        l_tot[u] = l;
    }

    // ---- KS=2: combine the two K-groups' unnormalized O,l via LDS ----
    if (KS == 2) {
        float* sc = (float*)smem;    // V arena dead after last barrier
        const int base = (wl * 64 + lane) * 34;
        if (g == 1) {
            #pragma unroll
            for (int u = 0; u < U; ++u) {
                #pragma unroll
                for (int gi = 0; gi < 4; ++gi)
                    #pragma unroll
                    for (int r = 0; r < 4; ++r)
                        sc[base + u * 16 + gi * 4 + r] = O[u][gi][r];
                sc[base + 32 + u] = l_tot[u];
            }
        }
        __syncthreads();
        if (g == 1) return;
        #pragma unroll
        for (int u = 0; u < U; ++u) {
            #pragma unroll
            for (int gi = 0; gi < 4; ++gi)
                #pragma unroll
                for (int r = 0; r < 4; ++r)
                    O[u][gi][r] += sc[base + u * 16 + gi * 4 + r];
            l_tot[u] += sc[base + 32 + u];
        }
    }

    if (MODE == 2) {
        // ---- final epilogue: gamma*O/l + residual -> fp32 out (B,64,N) ----
        const float gm = gamma_p[0];
        #pragma unroll
        for (int u = 0; u < U; ++u) {
            float inv = gm / l_tot[u];
            const int n = n0 + 16 * u + c16;
            #pragma unroll
            for (int gi = 0; gi < 4; ++gi) {
                #pragma unroll
                for (int r = 0; r < 4; ++r) {
                    size_t oidx = ((size_t)b * 64 + 16 * gi + 4 * q4 + r) * NQ + n;
                    out_f[oidx] = O[u][gi][r] * inv + resid[oidx];
                }
            }
        }
    } else {
        // ---- split epilogue: normalized bf16 partials (B,S,NQ,64) + l ----
        #pragma unroll
        for (int u = 0; u < U; ++u) {
            float inv = 1.0f / l_tot[u];
            bf16* dst = Opart + ((size_t)(b * NSPLIT + s) * NQ + n0 + 16 * u + c16) * 64 + q4 * 4;
            #pragma unroll
            for (int gi = 0; gi < 4; ++gi) {
                bf16x4 yv;
                #pragma unroll
                for (int r = 0; r < 4; ++r) yv[r] = (bf16)(O[u][gi][r] * inv);
                *(bf16x4*)(dst + 16 * gi) = yv;
            }
        }
        if (lane < 16) {
            #pragma unroll
            for (int u = 0; u < U; ++u)
                Lbuf[(b * NSPLIT + s) * NQ + n0 + 16 * u + lane] = l_tot[u];
        }
    }
}

// ---------------------------------------------------------------------------
// comb1kv: combine stage-1 partials (8 splits; weights = l_s) -> ox tile
// (32 x 64), then chain: otile = w_V ox + b_V; kpl = w_k otile + b_k;
// vp = w_v otile + b_v; qk2t = w_Q^T kpl; Gb = b_Q . kpl. Grid (32, 8).
// ---------------------------------------------------------------------------
__global__ __launch_bounds__(256) void comb1kv_kernel(
    const bf16* __restrict__ Opart, const float* __restrict__ Lbuf,
    const float* __restrict__ w_V, const float* __restrict__ b_V,
    const float* __restrict__ w_k, const float* __restrict__ b_k,
    const float* __restrict__ w_v, const float* __restrict__ b_v,
    const float* __restrict__ w_Q, const float* __restrict__ b_Q,
    bf16* __restrict__ qk2t, bf16* __restrict__ vp, float* __restrict__ Gb)
{
    __shared__ __align__(16) bf16 tile[32 * 72];
    __shared__ __align__(16) bf16 otile[32 * 72];
    __shared__ __align__(16) bf16 kpl[32 * 72];
    __shared__ float wbuf[32 * 8];
    const int t  = threadIdx.x;
    const int m0 = blockIdx.x * 32;
    const int b  = blockIdx.y;
    const int w  = t >> 6;
    const int lane = t & 63;

    WFrag wf;
    if      (w == 0) wf = load_wfrag<0>(w_V, lane);
    else if (w == 1) wf = load_wfrag<0>(w_k, lane);
    else if (w == 2) wf = load_wfrag<0>(w_v, lane);
    else             wf = load_wfrag<1>(w_Q, lane);

    if (t < 32) {
        int m = m0 + t;
        float ls[8], lt = 0.f;
        #pragma unroll
        for (int s = 0; s < 8; ++s) {
            ls[s] = Lbuf[(b * 8 + s) * 1024 + m];
            lt += ls[s];
        }
        float inv = 1.f / lt;
        #pragma unroll
        for (int s = 0; s < 8; ++s) wbuf[t * 8 + s] = ls[s] * inv;
    }
    __syncthreads();

    #pragma unroll
    for (int i = 0; i < 2; ++i) {
        int ml = i * 16 + (t >> 4);
        int c4 = (t & 15) * 4;
        const bf16* base = Opart + ((size_t)(b * 8) * 1024 + m0 + ml) * 64 + c4;
        float a0 = 0.f, a1 = 0.f, a2 = 0.f, a3 = 0.f;
        #pragma unroll
        for (int s = 0; s < 8; ++s) {
            bf16x4 v = *(const bf16x4*)(base + (size_t)s * 1024 * 64);
            float wg = wbuf[ml * 8 + s];
            a0 += (float)v[0] * wg; a1 += (float)v[1] * wg;
            a2 += (float)v[2] * wg; a3 += (float)v[3] * wg;
        }
        bf16x4 o; o[0] = (bf16)a0; o[1] = (bf16)a1; o[2] = (bf16)a2; o[3] = (bf16)a3;
        *(bf16x4*)&tile[ml * 72 + c4] = o;
    }
    __syncthreads();

    if (w == 0) proj_run<2>(tile, 2, wf, b_V, nullptr, 0, 0, 0, otile, lane);
    __syncthreads();
    if (w == 1) proj_run<2>(otile, 2, wf, b_k, nullptr, 0, 0, 0, kpl, lane);
    if (w == 2) proj_run<1>(otile, 2, wf, b_v, vp, 1024, b, m0, nullptr, lane);
    __syncthreads();
    if (w == 3) proj_run<0>(kpl, 2, wf, nullptr, qk2t, 1024, b, m0, nullptr, lane);
    if (w == 0 && lane < 32) {
        float acc = 0.f;
        #pragma unroll
        for (int c = 0; c < 64; ++c) acc += b_Q[c] * (float)kpl[lane * 72 + c];
        Gb[(size_t)b * 1024 + m0 + lane] = acc;
    }
}

// ---------------------------------------------------------------------------
extern "C" void kernel_launch(void* const* d_in, const int* in_sizes, int n_in,
                              void* d_out, int out_size, void* d_ws, size_t ws_size,
                              hipStream_t stream) {
    const float* x    = (const float*)d_in[0];
    const float* w_q  = (const float*)d_in[1];
    const float* b_q  = (const float*)d_in[2];
    const float* w_K  = (const float*)d_in[3];
    const float* b_K  = (const float*)d_in[4];   (void)b_K;  // cancels in softmax
    const float* w_V  = (const float*)d_in[5];
    const float* b_V  = (const float*)d_in[6];
    const float* w_Q  = (const float*)d_in[7];
    const float* b_Q  = (const float*)d_in[8];
    const float* w_k  = (const float*)d_in[9];
    const float* b_k  = (const float*)d_in[10];
    const float* w_v  = (const float*)d_in[11];
    const float* b_v  = (const float*)d_in[12];
    const float* gamma = (const float*)d_in[13];
    float* out = (float*)d_out;

    char* ws = (char*)d_ws;
    bf16*  xt    = (bf16*)ws;   ws += (size_t)8 * 4096 * 64 * 2;       // 4MB
    bf16*  xn    = (bf16*)ws;   ws += (size_t)8 * 4096 * 64 * 2;       // 4MB
    bf16*  qkt   = (bf16*)ws;   ws += (size_t)8 * 1024 * 64 * 2;       // 1MB
    bf16*  qk2t  = (bf16*)ws;   ws += (size_t)8 * 1024 * 64 * 2;       // 1MB
    bf16*  vp    = (bf16*)ws;   ws += (size_t)8 * 64 * 1024 * 2;       // 1MB
    bf16*  Opart = (bf16*)ws;   ws += (size_t)8 * 8 * 1024 * 64 * 2;   // 8MB
    float* Lb    = (float*)ws;  ws += (size_t)8 * 8 * 1024 * 4;        // 256KB
    float* Gb    = (float*)ws;  ws += (size_t)8 * 1024 * 4;            // 32KB

    // 1) cast/transpose/pool + qkt chain
    prep_kernel<<<dim3(32, 8), 256, 0, stream>>>(x, w_q, b_q, w_K, xt, xn, qkt);

    // 2) stage-1 flash on raw x: qkt (1024 q) vs xt/xn (L=4096), split x8
    flash_kernel<8, 1, 2, 1, false><<<dim3(8, 8, 8), 256, 0, stream>>>(
        qkt, xt, xn, 1024, 4096, Opart, Lb, nullptr, nullptr, nullptr, nullptr);

    // 3) combine + projection chain -> qk2t, vp, Gb
    comb1kv_kernel<<<dim3(32, 8), 256, 0, stream>>>(
        Opart, Lb, w_V, b_V, w_k, b_k, w_v, b_v, w_Q, b_Q, qk2t, vp, Gb);

    // 4) stage-2 flash, KS=2, per-key bias Gb, fused gamma+residual -> out
    flash_kernel<1, 2, 2, 2, true><<<dim3(32, 8, 1), 512, 0, stream>>>(
        xt, qk2t, vp, 4096, 1024, nullptr, nullptr, out, x, gamma, Gb);
}

// Round 8
// 132.563 us; speedup vs baseline: 1.1237x; 1.1237x over previous
//
#include <hip/hip_runtime.h>
#include <math.h>

// B=8, C=64, H=W=64, N=4096, N4=1024. bf16 MFMA, fp32 accumulate.
//
// ALGEBRAIC RESTRUCTURE (R2): no full-resolution projections.
//  Stage1: softmax(qp^T K(x)) == softmax((w_K^T qp)^T x); PV on raw x;
//          out1 = w_V (x a^T) + b_V applied at 1024 width in comb.
//  Stage2: Q(x)^T kp == x^T (w_Q^T kp) + gamma_m (per-key bias in flash2).
// R4: P kept in registers (cvt_pk_bf16 + permlane32/16 quad-transpose).
// R8 (= R5 + ONE isolated change): exp2-domain softmax -- log2e folded into
//     qkt/qk2t/Gb at prep/comb; flash uses raw v_exp_f32 (2^x), deleting
//     one v_mul per exp. K/V both via async-DMA LDS (R7 showed K-direct
//     regresses 16us: barrier-lockstep exposes L2 latency, 4x L2 traffic).
// Pipeline (4 kernels): prep, flash1 (split 8), comb1kv, flash2 (KS=2
// internal K-split, per-key bias, fused gamma+residual -> out).
// Flash: S^T/O^T form, 32 q/wave, async-DMA K/V tiles (stride-64 + chunk-rot
// swizzle), UNSHIFTED softmax (p=2^s', scores O(33) in log2 domain, fp32-safe).

typedef __bf16 bf16;
typedef __attribute__((ext_vector_type(4))) __bf16 bf16x4;
typedef __attribute__((ext_vector_type(8))) __bf16 bf16x8;
typedef __attribute__((ext_vector_type(4))) float f32x4;

constexpr float LOG2E = 1.4426950408889634f;

__device__ __forceinline__ void gl_lds16(const bf16* g, bf16* l) {
    __builtin_amdgcn_global_load_lds(
        (const __attribute__((address_space(1))) unsigned int*)g,
        (__attribute__((address_space(3))) unsigned int*)l,
        16, 0, 0);
}

// raw v_exp_f32: r = 2^x
__device__ __forceinline__ float vexp2(float x) {
    float r;
    asm("v_exp_f32 %0, %1" : "=v"(r) : "v"(x));
    return r;
}
// pack 2 f32 -> 2 bf16 in one u32 (lo = a, hi = b)
__device__ __forceinline__ unsigned cvtpk(float a, float b) {
    unsigned r;
    asm("v_cvt_pk_bf16_f32 %0, %1, %2" : "=v"(r) : "v"(a), "v"(b));
    return r;
}
// swap lanes [32..63] of a with [0..31] of b
__device__ __forceinline__ void swap32(unsigned &a, unsigned &b) {
    asm("v_permlane32_swap_b32 %0, %1" : "+v"(a), "+v"(b));
}
// swap lanes [16..31],[48..63] of a with [0..15],[32..47] of b
__device__ __forceinline__ void swap16(unsigned &a, unsigned &b) {
    asm("v_permlane16_swap_b32 %0, %1" : "+v"(a), "+v"(b));
}

// ---------------------------------------------------------------------------
// Weight fragments for a 64x64 1x1-conv as MFMA A-operand.
// WT=0: rows of W (W[o][c]); WT=1: transposed (W^T)[o][c] = W[c][o].
// sc: pre-scale (log2e folding into score-producing weights).
// ---------------------------------------------------------------------------
struct WFrag { bf16x8 f[4][2]; };

template<int WT>
__device__ __forceinline__ WFrag load_wfrag(const float* __restrict__ W, int lane,
                                            float sc = 1.0f) {
    const int c16 = lane & 15, q4 = lane >> 4;
    WFrag wf;
    #pragma unroll
    for (int to = 0; to < 4; ++to)
        #pragma unroll
        for (int h = 0; h < 2; ++h) {
            bf16 tmp[8];
            if (WT == 0) {
                const float* wp = W + (16 * to + c16) * 64 + q4 * 8 + 32 * h;
                float4 f0 = *(const float4*)wp;
                float4 f1 = *(const float4*)(wp + 4);
                tmp[0] = (bf16)(f0.x * sc); tmp[1] = (bf16)(f0.y * sc);
                tmp[2] = (bf16)(f0.z * sc); tmp[3] = (bf16)(f0.w * sc);
                tmp[4] = (bf16)(f1.x * sc); tmp[5] = (bf16)(f1.y * sc);
                tmp[6] = (bf16)(f1.z * sc); tmp[7] = (bf16)(f1.w * sc);
            } else {
                #pragma unroll
                for (int j = 0; j < 8; ++j)
                    tmp[j] = (bf16)(W[(q4 * 8 + 32 * h + j) * 64 + 16 * to + c16] * sc);
            }
            wf.f[to][h] = *(bf16x8*)tmp;
        }
    return wf;
}

// ---------------------------------------------------------------------------
// Per-wave projection of TN*16 rows x 64ch from LDS src (stride 72).
// OUT=0: global (B,N,64) row-major; OUT=1: global (B,64,N); OUT=2: LDS (72).
// ---------------------------------------------------------------------------
template<int OUT>
__device__ __forceinline__ void proj_run(
    const bf16* __restrict__ src, int TN, const WFrag& wf, const float* __restrict__ Bs,
    bf16* __restrict__ Y, int N, int b, int gn0, bf16* __restrict__ Yl, int lane)
{
    const int c16 = lane & 15, q4 = lane >> 4;
    for (int tn = 0; tn < TN; ++tn) {
        bf16x8 xb0 = *(const bf16x8*)&src[(16 * tn + c16) * 72 + q4 * 8];
        bf16x8 xb1 = *(const bf16x8*)&src[(16 * tn + c16) * 72 + q4 * 8 + 32];
        #pragma unroll
        for (int to = 0; to < 4; ++to) {
            f32x4 acc = (f32x4){0.f, 0.f, 0.f, 0.f};
            acc = __builtin_amdgcn_mfma_f32_16x16x32_bf16(wf.f[to][0], xb0, acc, 0, 0, 0);
            acc = __builtin_amdgcn_mfma_f32_16x16x32_bf16(wf.f[to][1], xb1, acc, 0, 0, 0);
            float bias[4] = {0.f, 0.f, 0.f, 0.f};
            if (Bs) {
                float4 b4 = *(const float4*)(Bs + 16 * to + q4 * 4);
                bias[0] = b4.x; bias[1] = b4.y; bias[2] = b4.z; bias[3] = b4.w;
            }
            if (OUT == 0) {
                bf16x4 yv;
                #pragma unroll
                for (int r = 0; r < 4; ++r) yv[r] = (bf16)(acc[r] + bias[r]);
                *(bf16x4*)(Y + ((size_t)b * N + gn0 + 16 * tn + c16) * 64 + 16 * to + 4 * q4) = yv;
            } else if (OUT == 1) {
                #pragma unroll
                for (int r = 0; r < 4; ++r)
                    Y[((size_t)b * 64 + 16 * to + 4 * q4 + r) * N + gn0 + 16 * tn + c16] =
                        (bf16)(acc[r] + bias[r]);
            } else {
                bf16x4 yv;
                #pragma unroll
                for (int r = 0; r < 4; ++r) yv[r] = (bf16)(acc[r] + bias[r]);
                *(bf16x4*)&Yl[(16 * tn + c16) * 72 + 16 * to + 4 * q4] = yv;
            }
        }
    }
}

// ---------------------------------------------------------------------------
// prep: x (B,64,4096) fp32 -> xt (B,4096,64) bf16 (transposed raw x),
// xn (B,64,4096) bf16 (cast raw x), qkt (B,1024,64) = log2e*w_K^T(w_q xp+b_q).
// ---------------------------------------------------------------------------
__global__ __launch_bounds__(256) void prep_kernel(
    const float* __restrict__ x,
    const float* __restrict__ w_q, const float* __restrict__ b_q,
    const float* __restrict__ w_K,
    bf16* __restrict__ xt, bf16* __restrict__ xn, bf16* __restrict__ qkt)
{
    __shared__ float tile[128 * 65];
    __shared__ __align__(16) bf16 xpb[32 * 72];
    __shared__ __align__(16) bf16 qtile[32 * 72];
    const int t  = threadIdx.x;
    const int h2 = blockIdx.x;
    const int b  = blockIdx.y;
    const int n0 = h2 * 128;

    #pragma unroll
    for (int i = 0; i < 32; ++i) {
        int lin = i * 256 + t;
        int n = lin & 127, c = lin >> 7;
        tile[n * 65 + c] = x[((size_t)b * 64 + c) * 4096 + n0 + n];
    }
    __syncthreads();
    {   // 2x2 avg pool of the 128-n tile -> 32 pooled rows
        int wp = t & 31, c0 = (t >> 5) * 8;
        bf16 tmp[8];
        #pragma unroll
        for (int j = 0; j < 8; ++j) {
            float a = tile[(2 * wp) * 65 + c0 + j] + tile[(2 * wp + 1) * 65 + c0 + j]
                    + tile[(64 + 2 * wp) * 65 + c0 + j] + tile[(64 + 2 * wp + 1) * 65 + c0 + j];
            tmp[j] = (bf16)(0.25f * a);
        }
        *(bf16x8*)&xpb[wp * 72 + c0] = *(bf16x8*)tmp;
    }
    __syncthreads();

    // xt: transposed bf16 cast (coalesced 16B stores)
    #pragma unroll
    for (int i = 0; i < 4; ++i) {
        int slot = i * 256 + t;
        int n = slot >> 3, c0 = (slot & 7) * 8;
        bf16 tmp[8];
        #pragma unroll
        for (int j = 0; j < 8; ++j) tmp[j] = (bf16)tile[n * 65 + c0 + j];
        *(bf16x8*)&xt[((size_t)b * 4096 + n0 + n) * 64 + c0] = *(bf16x8*)tmp;
    }
    // xn: straight bf16 cast (channel-major)
    #pragma unroll
    for (int i = 0; i < 4; ++i) {
        int slot = i * 256 + t;
        int c = slot >> 4, n8 = slot & 15;
        bf16 tmp[8];
        #pragma unroll
        for (int j = 0; j < 8; ++j) tmp[j] = (bf16)tile[(n8 * 8 + j) * 65 + c];
        *(bf16x8*)&xn[((size_t)b * 64 + c) * 4096 + n0 + n8 * 8] = *(bf16x8*)tmp;
    }
    // wave 3: qkt chain (qtile = w_q xp + b_q; qkt = log2e * w_K^T qtile)
    if ((t >> 6) == 3) {
        const int lane = t & 63;
        WFrag wfq  = load_wfrag<0>(w_q, lane);
        WFrag wfKT = load_wfrag<1>(w_K, lane, LOG2E);
        proj_run<2>(xpb, 2, wfq, b_q, nullptr, 0, 0, 0, qtile, lane);
        asm volatile("s_waitcnt lgkmcnt(0)" ::: "memory");
        proj_run<0>(qtile, 2, wfKT, nullptr, qkt, 1024, b, h2 * 32, nullptr, lane);
    }
}

// ---------------------------------------------------------------------------
// Flash, S^T/O^T, U*16 q/wave. KS=1: 4 waves. KS=2: 8 waves, two 4-wave
// groups each own half of L, unnormalized O,l combined via LDS (exact:
// softmax unshifted). P kept in registers via cvt_pk + permlane quad-
// transpose (no Pw LDS). BIAS: per-key fp32 additive score bias.
// Scores in log2 domain (Q-side and bias pre-scaled by log2e): p = 2^s.
//   Qt: (B,NQ,64), Kt: (B,L,64), Vn: (B,64,L) bf16.
//   MODE=1: split partials, Opart (B,S,NQ,64) normalized bf16 + l.
//   MODE=2: final: out_f = gamma*O/l + resid (fp32, channel-major).
// ---------------------------------------------------------------------------
template<int NSPLIT, int MODE, int U, int KS, bool BIAS>
__global__ __launch_bounds__(256 * KS, KS == 1 ? 3 : 2) void flash_kernel(
    const bf16* __restrict__ Qt, const bf16* __restrict__ Kt,
    const bf16* __restrict__ Vn, int NQ, int L,
    bf16* __restrict__ Opart, float* __restrict__ Lbuf,
    float* __restrict__ out_f, const float* __restrict__ resid,
    const float* __restrict__ gamma_p, const float* __restrict__ Gb)
{
    const int tid  = threadIdx.x;
    const int lane = tid & 63;
    const int w    = tid >> 6;
    const int wl   = w & 3;          // wave-in-group
    const int g    = w >> 2;         // K-split group
    const int c16  = lane & 15;
    const int q4   = lane >> 4;
    const int b    = blockIdx.y;
    const int n0   = blockIdx.x * (64 * U) + wl * (16 * U);
    const int s    = (NSPLIT > 1) ? blockIdx.z : 0;
    const int SL   = L / (NSPLIT * KS);
    const int k0   = (s * KS + g) * SL;
    const int ntiles = SL / 64;

    // K/V double-buffer arena; KS=2 epilogue overlays fp32 scratch on it
    // (dead after the last in-loop barrier). KS=2: 64KB >= 34.8KB scratch.
    __shared__ __align__(16) char smem[(size_t)KS * 2 * 4096 * 2 * 2];
    bf16* Ksm = (bf16*)smem;                          // [KS][2][4096]
    bf16* Vsm = (bf16*)(smem + (size_t)KS * 2 * 4096 * 2);

    const int rl8 = lane >> 3;               // 0..7
    const int cg  = ((lane & 7) - rl8) & 7;  // rotated source chunk

    const bf16* Kb = Kt + (size_t)b * L * 64;
    const bf16* Vb = Vn + (size_t)b * 64 * L;

    bf16x8 bq[U][2];
    #pragma unroll
    for (int u = 0; u < U; ++u) {
        const bf16* qrow = Qt + ((size_t)b * NQ + n0 + 16 * u + c16) * 64 + q4 * 8;
        bq[u][0] = *(const bf16x8*)(qrow);
        bq[u][1] = *(const bf16x8*)(qrow + 32);
    }

    f32x4 O[U][4];
    #pragma unroll
    for (int u = 0; u < U; ++u)
        #pragma unroll
        for (int gi = 0; gi < 4; ++gi) O[u][gi] = (f32x4){0.f, 0.f, 0.f, 0.f};
    float l_acc[U];
    #pragma unroll
    for (int u = 0; u < U; ++u) l_acc[u] = 0.f;

    #pragma unroll
    for (int j = 0; j < 2; ++j) {
        const int row = 16 * wl + 8 * j + rl8;
        gl_lds16(Kb + (size_t)(k0 + row) * 64 + cg * 8, &Ksm[(g * 2 + 0) * 4096 + (16 * wl + 8 * j) * 64]);
        gl_lds16(Vb + (size_t)row * L + k0 + cg * 8,    &Vsm[(g * 2 + 0) * 4096 + (16 * wl + 8 * j) * 64]);
    }
    __syncthreads();

    for (int it = 0; it < ntiles; ++it) {
        const int buf = it & 1;
        if (it + 1 < ntiles) {
            const int kn = k0 + (it + 1) * 64;
            #pragma unroll
            for (int j = 0; j < 2; ++j) {
                const int row = 16 * wl + 8 * j + rl8;
                gl_lds16(Kb + (size_t)(kn + row) * 64 + cg * 8,
                         &Ksm[(g * 2 + (buf ^ 1)) * 4096 + (16 * wl + 8 * j) * 64]);
                gl_lds16(Vb + (size_t)row * L + kn + cg * 8,
                         &Vsm[(g * 2 + (buf ^ 1)) * 4096 + (16 * wl + 8 * j) * 64]);
            }
        }

        // ---- S^T, K-frags shared across query sets (swizzled reads) ----
        f32x4 sv[U][4];
        #pragma unroll
        for (int t = 0; t < 4; ++t) {
            const bf16* krow = &Ksm[(g * 2 + buf) * 4096 + (16 * t + c16) * 64];
            bf16x8 ak0 = *(const bf16x8*)&krow[((q4 + c16) & 7) * 8];
            bf16x8 ak1 = *(const bf16x8*)&krow[((q4 + 4 + c16) & 7) * 8];
            #pragma unroll
            for (int u = 0; u < U; ++u) {
                f32x4 z = (f32x4){0.f, 0.f, 0.f, 0.f};
                z = __builtin_amdgcn_mfma_f32_16x16x32_bf16(ak0, bq[u][0], z, 0, 0, 0);
                sv[u][t] = __builtin_amdgcn_mfma_f32_16x16x32_bf16(ak1, bq[u][1], z, 0, 0, 0);
            }
        }

        // ---- per-key bias (stage 2, log2 domain): key = k0+64it+16t+4q4+r ----
        float4 gb[4];
        if (BIAS) {
            #pragma unroll
            for (int t = 0; t < 4; ++t)
                gb[t] = *(const float4*)&Gb[(size_t)b * 1024 + k0 + it * 64 + 16 * t + 4 * q4];
        }

        // ---- unshifted softmax (p = 2^s) + in-register P quad-transpose ----
        bf16x8 pfs[U][2];
        #pragma unroll
        for (int u = 0; u < U; ++u) {
            #pragma unroll
            for (int t = 0; t < 4; ++t)
                #pragma unroll
                for (int r = 0; r < 4; ++r) {
                    float sval = sv[u][t][r];
                    if (BIAS) sval += ((const float*)&gb[t])[r];
                    float p = vexp2(sval);
                    sv[u][t][r] = p;
                    l_acc[u] += p;
                }
            unsigned A0 = cvtpk(sv[u][0][0], sv[u][0][1]);
            unsigned A1 = cvtpk(sv[u][0][2], sv[u][0][3]);
            unsigned A2 = cvtpk(sv[u][2][0], sv[u][2][1]);
            unsigned A3 = cvtpk(sv[u][2][2], sv[u][2][3]);
            unsigned B0 = cvtpk(sv[u][1][0], sv[u][1][1]);
            unsigned B1 = cvtpk(sv[u][1][2], sv[u][1][3]);
            unsigned B2 = cvtpk(sv[u][3][0], sv[u][3][1]);
            unsigned B3 = cvtpk(sv[u][3][2], sv[u][3][3]);
            swap32(A0, B0); swap16(A0, B0);
            swap32(A1, B1); swap16(A1, B1);
            swap32(A2, B2); swap16(A2, B2);
            swap32(A3, B3); swap16(A3, B3);
            union { unsigned wd[4]; bf16x8 v; } p0, p1;
            p0.wd[0] = A0; p0.wd[1] = A1; p0.wd[2] = B0; p0.wd[3] = B1;
            p1.wd[0] = A2; p1.wd[1] = A3; p1.wd[2] = B2; p1.wd[3] = B3;
            pfs[u][0] = p0.v;
            pfs[u][1] = p1.v;
        }

        // ---- PV: V-frags shared across query sets (swizzled reads) ----
        #pragma unroll
        for (int h = 0; h < 2; ++h) {
            #pragma unroll
            for (int gi = 0; gi < 4; ++gi) {
                bf16x8 av = *(const bf16x8*)&Vsm[(g * 2 + buf) * 4096 +
                                                 (16 * gi + c16) * 64 + ((4 * h + q4 + c16) & 7) * 8];
                #pragma unroll
                for (int u = 0; u < U; ++u)
                    O[u][gi] = __builtin_amdgcn_mfma_f32_16x16x32_bf16(av, pfs[u][h], O[u][gi], 0, 0, 0);
            }
        }
        __syncthreads();
    }

    // ---- reduce l across quads ----
    float l_tot[U];
    #pragma unroll
    for (int u = 0; u < U; ++u) {
        float l = l_acc[u];
        l += __shfl_xor(l, 16);
        l += __shfl_xor(l, 32);
        l_tot[u] = l;
    }

    // ---- KS=2: combine the two K-groups' unnormalized O,l via LDS ----
    if (KS == 2) {
        float* sc = (float*)smem;    // K/V arena dead after last barrier
        const int base = (wl * 64 + lane) * 34;
        if (g == 1) {
            #pragma unroll
            for (int u = 0; u < U; ++u) {
                #pragma unroll
                for (int gi = 0; gi < 4; ++gi)
                    #pragma unroll
                    for (int r = 0; r < 4; ++r)
                        sc[base + u * 16 + gi * 4 + r] = O[u][gi][r];
                sc[base + 32 + u] = l_tot[u];
            }
        }
        __syncthreads();
        if (g == 1) return;
        #pragma unroll
        for (int u = 0; u < U; ++u) {
            #pragma unroll
            for (int gi = 0; gi < 4; ++gi)
                #pragma unroll
                for (int r = 0; r < 4; ++r)
                    O[u][gi][r] += sc[base + u * 16 + gi * 4 + r];
            l_tot[u] += sc[base + 32 + u];
        }
    }

    if (MODE == 2) {
        // ---- final epilogue: gamma*O/l + residual -> fp32 out (B,64,N) ----
        const float gm = gamma_p[0];
        #pragma unroll
        for (int u = 0; u < U; ++u) {
            float inv = gm / l_tot[u];
            const int n = n0 + 16 * u + c16;
            #pragma unroll
            for (int gi = 0; gi < 4; ++gi) {
                #pragma unroll
                for (int r = 0; r < 4; ++r) {
                    size_t oidx = ((size_t)b * 64 + 16 * gi + 4 * q4 + r) * NQ + n;
                    out_f[oidx] = O[u][gi][r] * inv + resid[oidx];
                }
            }
        }
    } else {
        // ---- split epilogue: normalized bf16 partials (B,S,NQ,64) + l ----
        #pragma unroll
        for (int u = 0; u < U; ++u) {
            float inv = 1.0f / l_tot[u];
            bf16* dst = Opart + ((size_t)(b * NSPLIT + s) * NQ + n0 + 16 * u + c16) * 64 + q4 * 4;
            #pragma unroll
            for (int gi = 0; gi < 4; ++gi) {
                bf16x4 yv;
                #pragma unroll
                for (int r = 0; r < 4; ++r) yv[r] = (bf16)(O[u][gi][r] * inv);
                *(bf16x4*)(dst + 16 * gi) = yv;
            }
        }
        if (lane < 16) {
            #pragma unroll
            for (int u = 0; u < U; ++u)
                Lbuf[(b * NSPLIT + s) * NQ + n0 + 16 * u + lane] = l_tot[u];
        }
    }
}

// ---------------------------------------------------------------------------
// comb1kv: combine stage-1 partials (8 splits; weights = l_s) -> ox tile
// (32 x 64), then chain: otile = w_V ox + b_V; kpl = w_k otile + b_k;
// vp = w_v otile + b_v; qk2t = log2e * w_Q^T kpl; Gb = log2e * b_Q . kpl.
// Grid (32, 8).
// ---------------------------------------------------------------------------
__global__ __launch_bounds__(256) void comb1kv_kernel(
    const bf16* __restrict__ Opart, const float* __restrict__ Lbuf,
    const float* __restrict__ w_V, const float* __restrict__ b_V,
    const float* __restrict__ w_k, const float* __restrict__ b_k,
    const float* __restrict__ w_v, const float* __restrict__ b_v,
    const float* __restrict__ w_Q, const float* __restrict__ b_Q,
    bf16* __restrict__ qk2t, bf16* __restrict__ vp, float* __restrict__ Gb)
{
    __shared__ __align__(16) bf16 tile[32 * 72];
    __shared__ __align__(16) bf16 otile[32 * 72];
    __shared__ __align__(16) bf16 kpl[32 * 72];
    __shared__ float wbuf[32 * 8];
    const int t  = threadIdx.x;
    const int m0 = blockIdx.x * 32;
    const int b  = blockIdx.y;
    const int w  = t >> 6;
    const int lane = t & 63;

    WFrag wf;
    if      (w == 0) wf = load_wfrag<0>(w_V, lane);
    else if (w == 1) wf = load_wfrag<0>(w_k, lane);
    else if (w == 2) wf = load_wfrag<0>(w_v, lane);
    else             wf = load_wfrag<1>(w_Q, lane, LOG2E);

    if (t < 32) {
        int m = m0 + t;
        float ls[8], lt = 0.f;
        #pragma unroll
        for (int s = 0; s < 8; ++s) {
            ls[s] = Lbuf[(b * 8 + s) * 1024 + m];
            lt += ls[s];
        }
        float inv = 1.f / lt;
        #pragma unroll
        for (int s = 0; s < 8; ++s) wbuf[t * 8 + s] = ls[s] * inv;
    }
    __syncthreads();

    #pragma unroll
    for (int i = 0; i < 2; ++i) {
        int ml = i * 16 + (t >> 4);
        int c4 = (t & 15) * 4;
        const bf16* base = Opart + ((size_t)(b * 8) * 1024 + m0 + ml) * 64 + c4;
        float a0 = 0.f, a1 = 0.f, a2 = 0.f, a3 = 0.f;
        #pragma unroll
        for (int s = 0; s < 8; ++s) {
            bf16x4 v = *(const bf16x4*)(base + (size_t)s * 1024 * 64);
            float wg = wbuf[ml * 8 + s];
            a0 += (float)v[0] * wg; a1 += (float)v[1] * wg;
            a2 += (float)v[2] * wg; a3 += (float)v[3] * wg;
        }
        bf16x4 o; o[0] = (bf16)a0; o[1] = (bf16)a1; o[2] = (bf16)a2; o[3] = (bf16)a3;
        *(bf16x4*)&tile[ml * 72 + c4] = o;
    }
    __syncthreads();

    if (w == 0) proj_run<2>(tile, 2, wf, b_V, nullptr, 0, 0, 0, otile, lane);
    __syncthreads();
    if (w == 1) proj_run<2>(otile, 2, wf, b_k, nullptr, 0, 0, 0, kpl, lane);
    if (w == 2) proj_run<1>(otile, 2, wf, b_v, vp, 1024, b, m0, nullptr, lane);
    __syncthreads();
    if (w == 3) proj_run<0>(kpl, 2, wf, nullptr, qk2t, 1024, b, m0, nullptr, lane);
    if (w == 0 && lane < 32) {
        float acc = 0.f;
        #pragma unroll
        for (int c = 0; c < 64; ++c) acc += b_Q[c] * (float)kpl[lane * 72 + c];
        Gb[(size_t)b * 1024 + m0 + lane] = acc * LOG2E;
    }
}

// ---------------------------------------------------------------------------
extern "C" void kernel_launch(void* const* d_in, const int* in_sizes, int n_in,
                              void* d_out, int out_size, void* d_ws, size_t ws_size,
                              hipStream_t stream) {
    const float* x    = (const float*)d_in[0];
    const float* w_q  = (const float*)d_in[1];
    const float* b_q  = (const float*)d_in[2];
    const float* w_K  = (const float*)d_in[3];
    const float* b_K  = (const float*)d_in[4];   (void)b_K;  // cancels in softmax
    const float* w_V  = (const float*)d_in[5];
    const float* b_V  = (const float*)d_in[6];
    const float* w_Q  = (const float*)d_in[7];
    const float* b_Q  = (const float*)d_in[8];
    const float* w_k  = (const float*)d_in[9];
    const float* b_k  = (const float*)d_in[10];
    const float* w_v  = (const float*)d_in[11];
    const float* b_v  = (const float*)d_in[12];
    const float* gamma = (const float*)d_in[13];
    float* out = (float*)d_out;

    char* ws = (char*)d_ws;
    bf16*  xt    = (bf16*)ws;   ws += (size_t)8 * 4096 * 64 * 2;       // 4MB
    bf16*  xn    = (bf16*)ws;   ws += (size_t)8 * 4096 * 64 * 2;       // 4MB
    bf16*  qkt   = (bf16*)ws;   ws += (size_t)8 * 1024 * 64 * 2;       // 1MB
    bf16*  qk2t  = (bf16*)ws;   ws += (size_t)8 * 1024 * 64 * 2;       // 1MB
    bf16*  vp    = (bf16*)ws;   ws += (size_t)8 * 64 * 1024 * 2;       // 1MB
    bf16*  Opart = (bf16*)ws;   ws += (size_t)8 * 8 * 1024 * 64 * 2;   // 8MB
    float* Lb    = (float*)ws;  ws += (size_t)8 * 8 * 1024 * 4;        // 256KB
    float* Gb    = (float*)ws;  ws += (size_t)8 * 1024 * 4;            // 32KB

    // 1) cast/transpose/pool + qkt chain (log2e folded)
    prep_kernel<<<dim3(32, 8), 256, 0, stream>>>(x, w_q, b_q, w_K, xt, xn, qkt);

    // 2) stage-1 flash on raw x: qkt (1024 q) vs xt/xn (L=4096), split x8
    flash_kernel<8, 1, 2, 1, false><<<dim3(8, 8, 8), 256, 0, stream>>>(
        qkt, xt, xn, 1024, 4096, Opart, Lb, nullptr, nullptr, nullptr, nullptr);

    // 3) combine + projection chain -> qk2t, vp, Gb (log2e folded)
    comb1kv_kernel<<<dim3(32, 8), 256, 0, stream>>>(
        Opart, Lb, w_V, b_V, w_k, b_k, w_v, b_v, w_Q, b_Q, qk2t, vp, Gb);

    // 4) stage-2 flash, KS=2, per-key bias Gb, fused gamma+residual -> out
    flash_kernel<1, 2, 2, 2, true><<<dim3(32, 8, 1), 512, 0, stream>>>(
        xt, qk2t, vp, 4096, 1024, nullptr, nullptr, out, x, gamma, Gb);
}